// Round 14
// baseline (178.166 us; speedup 1.0000x reference)
//
#include <hip/hip_runtime.h>
#include <hip/hip_fp16.h>

#define NITER 3
#define LAMBDA 0.01f
#define EPS 1e-9f
#define LOG2PI 1.8378770664093453f

#define DIN 12
#define CIN 8
#define NI 216      // 27 * 8 input capsule-taps
#define NO 16       // output capsules
#define PPAD 20     // sPT row stride (floats)
#define RSTR 216    // sRaT row stride (floats)

// 512 threads = 16 o x 32 j. Thread (o,j) owns taps i = j+32k (k=0..6, padded).
// Votes packed fp16 (vop[7][8] = 56 regs), computed once. sPT/sRaT aliased
// (LDS 20.3 KB). NEW vs R13: __launch_bounds__(512, 4) -> compiler must fit
// TOTAL regs (arch+acc, unified gfx950 file) in 512/4 = 128 so 2 blocks/CU
// co-reside. R13 demand ~80-100 regs -> fits without spill (unlike R4's 180).
__global__ __launch_bounds__(512, 4)
void caps_em_kernel(const float* __restrict__ pose,
                    const float* __restrict__ act,
                    const float* __restrict__ W,
                    const float* __restrict__ beta_v,
                    const float* __restrict__ beta_a,
                    float* __restrict__ out)
{
    // union region: max(sPT 216*20*4 = 17280 B, sRaT 16*216*4 = 13824 B)
    __shared__ __align__(16) char uBuf[17280];
    float (*sPT)[PPAD]  = (float (*)[PPAD])uBuf;   // valid until last prologue read
    float (*sRaT)[RSTR] = (float (*)[RSTR])uBuf;   // valid from e-step (it=0) on
    __shared__ float sAct[NI];
    __shared__ __align__(16) float sPoseM[NO][16];   // row-major [o][r*4+c]
    __shared__ __align__(16) float sIvM[NO][16];
    __shared__ float sCo[NO];

    const int t = threadIdx.x;
    const int b = blockIdx.x;            // 0..999 -> (od,oh,ow)
    const int od = b / 100;
    const int rem = b - od * 100;
    const int oh = rem / 10;
    const int ow = rem - oh * 10;

    const int o = t >> 5;                // output capsule 0..15
    const int j = t & 31;                // i-lane 0..31

    // ---------- stage P (transposed) + act ----------
    for (int u = t; u < NI * 4; u += 512) {
        int i = u >> 2, q = u & 3;       // q = source row of the 4x4
        int ci = i & 7, n = i >> 3;
        int kw = n % 3, n2 = n / 3;
        int kh = n2 % 3, kd = n2 / 3;
        const float4 v = *(const float4*)&pose[((((od + kd) * DIN + (oh + kh)) * DIN + (ow + kw)) * CIN + ci) * 16 + q * 4];
        sPT[i][0 + q]  = v.x;
        sPT[i][4 + q]  = v.y;
        sPT[i][8 + q]  = v.z;
        sPT[i][12 + q] = v.w;
    }
    if (t < NI) {
        int i = t;
        int ci = i & 7, n = i >> 3;
        int kw = n % 3, n2 = n / 3;
        int kh = n2 % 3, kd = n2 / 3;
        sAct[i] = act[(((od + kd) * DIN + (oh + kh)) * DIN + (ow + kw)) * CIN + ci] + EPS;
    }
    const float bv_o = beta_v[o];
    const float ba_o = beta_a[o];
    __syncthreads();

    // ---------- votes ONCE, per-k interleaved load+compute (low reg spike) ----------
    const float4* W4 = (const float4*)W;        // idx = (i*16 + o)*4 + r
    __half2 vop[7][8];                          // vop[k][p] = (e=2p, e=2p+1)
#pragma unroll
    for (int k = 0; k < 7; ++k) {
        const int ip = min(j + 32 * k, NI - 1);
        const float4* Wp = W4 + (ip * 16 + o) * 4;
        const float4 w0 = Wp[0], w1 = Wp[1], w2 = Wp[2], w3 = Wp[3];
        float v16[16];
#pragma unroll
        for (int cc = 0; cc < 4; ++cc) {
            const float4 pt = *(const float4*)&sPT[ip][cc * 4];   // P[0..3][cc]
            v16[0 * 4 + cc]  = fmaf(w0.w, pt.w, fmaf(w0.z, pt.z, fmaf(w0.y, pt.y, w0.x * pt.x)));
            v16[1 * 4 + cc]  = fmaf(w1.w, pt.w, fmaf(w1.z, pt.z, fmaf(w1.y, pt.y, w1.x * pt.x)));
            v16[2 * 4 + cc]  = fmaf(w2.w, pt.w, fmaf(w2.z, pt.z, fmaf(w2.y, pt.y, w2.x * pt.x)));
            v16[3 * 4 + cc]  = fmaf(w3.w, pt.w, fmaf(w3.z, pt.z, fmaf(w3.y, pt.y, w3.x * pt.x)));
        }
#pragma unroll
        for (int p = 0; p < 8; ++p) {
            vop[k][p] = __floats2half2_rn(v16[2 * p], v16[2 * p + 1]);
        }
    }
    // All sPT reads done by every thread before it reaches B2 (it=0); first sRaT
    // write happens only after B2 -> aliasing is race-free.

    const int b4 = (j >> 4) & 1, b3 = (j >> 3) & 1, b2 = (j >> 2) & 1;
    const bool lastPartial = (j >= 24);  // k=6 tap i=192+j valid only for j<24
    const int eL = (j >> 2) & 7;         // this lane's element within each half

    for (int it = 0; it < NITER; ++it) {
        // ---------- ra for own taps ----------
        float rak[7];
#pragma unroll
        for (int k = 0; k < 7; ++k) {
            const int ip = min(j + 32 * k, NI - 1);
            float ra = (it == 0) ? sAct[ip] * 0.0625f : sRaT[o][ip];
            if (k == 6 && lastPartial) ra = 0.f;
            rak[k] = ra;
        }
        float rs = rak[0] + rak[1] + rak[2] + rak[3] + rak[4] + rak[5] + rak[6];
        rs += __shfl_xor(rs, 16);
        rs += __shfl_xor(rs, 8);
        rs += __shfl_xor(rs, 4);
        rs += __shfl_xor(rs, 2);
        rs += __shfl_xor(rs, 1);
        const float inv_rs = 1.0f / rs;

        float peA, ivA, lvA, peB, ivB, lvB;
        // ======== half sweeps: h=0 -> elements 0..7, h=1 -> 8..15 ========
#pragma unroll
        for (int h = 0; h < 2; ++h) {
            float m1[8], m2[8];
#pragma unroll
            for (int q = 0; q < 8; ++q) { m1[q] = 0.f; m2[q] = 0.f; }
#pragma unroll
            for (int k = 0; k < 7; ++k) {
                const float ra = rak[k];
#pragma unroll
                for (int p = 0; p < 4; ++p) {
                    const float2 f = __half22float2(vop[k][h * 4 + p]);
                    const float rv0 = ra * f.x;
                    const float rv1 = ra * f.y;
                    m1[2 * p]     += rv0;
                    m1[2 * p + 1] += rv1;
                    m2[2 * p]     = fmaf(rv0, f.x, m2[2 * p]);
                    m2[2 * p + 1] = fmaf(rv1, f.y, m2[2 * p + 1]);
                }
            }
            // 3-halving tree over 32 lanes: e_local = b4*4 + b3*2 + b2 = (j>>2)&7
#pragma unroll
            for (int q = 0; q < 4; ++q) {
                float s1 = b4 ? m1[q] : m1[q + 4];
                float s2 = b4 ? m2[q] : m2[q + 4];
                m1[q] = (b4 ? m1[q + 4] : m1[q]) + __shfl_xor(s1, 16);
                m2[q] = (b4 ? m2[q + 4] : m2[q]) + __shfl_xor(s2, 16);
            }
#pragma unroll
            for (int q = 0; q < 2; ++q) {
                float s1 = b3 ? m1[q] : m1[q + 2];
                float s2 = b3 ? m2[q] : m2[q + 2];
                m1[q] = (b3 ? m1[q + 2] : m1[q]) + __shfl_xor(s1, 8);
                m2[q] = (b3 ? m2[q + 2] : m2[q]) + __shfl_xor(s2, 8);
            }
            {
                float s1 = b2 ? m1[0] : m1[1];
                float s2 = b2 ? m2[0] : m2[1];
                m1[0] = (b2 ? m1[1] : m1[0]) + __shfl_xor(s1, 4);
                m2[0] = (b2 ? m2[1] : m2[0]) + __shfl_xor(s2, 4);
            }
            m1[0] += __shfl_xor(m1[0], 2);
            m2[0] += __shfl_xor(m2[0], 2);
            m1[0] += __shfl_xor(m1[0], 1);
            m2[0] += __shfl_xor(m2[0], 1);

            const float pe = m1[0] * inv_rs;
            const float ve = fmaxf(m2[0] * inv_rs - pe * pe, 0.0f) + EPS;
            if (h == 0) { peA = pe; ivA = 1.0f / ve; lvA = __logf(ve); }
            else        { peB = pe; ivB = 1.0f / ve; lvB = __logf(ve); }
        }

        // SL: each lane holds lv for 2 of 16 elements, 4-fold duplicated
        float SL = lvA + lvB;
        SL += __shfl_xor(SL, 1);
        SL += __shfl_xor(SL, 2);
        SL += __shfl_xor(SL, 4);
        SL += __shfl_xor(SL, 8);
        SL += __shfl_xor(SL, 16);
        SL *= 0.25f;

        const float cost  = rs * (16.0f * bv_o + 0.5f * SL);
        const float logit = LAMBDA * (ba_o - cost);

        if (it == NITER - 1) {
            if ((j & 3) == 0) {
                out[(b * NO + o) * 16 + eL]     = peA;
                out[(b * NO + o) * 16 + 8 + eL] = peB;
            }
            if (j == 0) out[256000 + b * NO + o] = 1.0f / (1.0f + __expf(-logit));
            return;
        }

        const float log_a = (logit >= 0.0f) ? -log1pf(__expf(-logit))
                                            : logit - log1pf(__expf(logit));
        if ((j & 3) == 0) {
            sPoseM[o][eL]     = peA;
            sPoseM[o][8 + eL] = peB;
            sIvM[o][eL]       = ivA;
            sIvM[o][8 + eL]   = ivB;
        }
        if (j == 0) sCo[o] = log_a - 0.5f * SL - 8.0f * LOG2PI;
        __syncthreads();   // B2: pose/iv/Co ready (also fences last sPT reads, it=0)

        // ---------- e-step: q-form from stored votes, two halves, qacc[7] ----------
        float qacc[7];
#pragma unroll
        for (int k = 0; k < 7; ++k) qacc[k] = 0.f;
#pragma unroll
        for (int h = 0; h < 2; ++h) {
            float pv[8], iv8[8];
            *(float4*)&pv[0]  = *(const float4*)&sPoseM[o][h * 8];
            *(float4*)&pv[4]  = *(const float4*)&sPoseM[o][h * 8 + 4];
            *(float4*)&iv8[0] = *(const float4*)&sIvM[o][h * 8];
            *(float4*)&iv8[4] = *(const float4*)&sIvM[o][h * 8 + 4];
#pragma unroll
            for (int k = 0; k < 7; ++k) {
                float q = qacc[k];
#pragma unroll
                for (int p = 0; p < 4; ++p) {
                    const float2 f = __half22float2(vop[k][h * 4 + p]);
                    const float d0 = f.x - pv[2 * p];
                    const float d1 = f.y - pv[2 * p + 1];
                    q = fmaf(d0 * d0, iv8[2 * p], q);
                    q = fmaf(d1 * d1, iv8[2 * p + 1], q);
                }
                qacc[k] = q;
            }
        }
        {
            const float Co = sCo[o];
#pragma unroll
            for (int k = 0; k < 7; ++k) {
                if (!(k == 6 && lastPartial)) {
                    sRaT[o][j + 32 * k] = Co - 0.5f * qacc[k];   // pre-norm logit
                }
            }
        }
        __syncthreads();   // B3: logits ready

        // ---------- R update: softmax over o, times act ----------
        if (t < NI) {
            float l[16];
            float mx = -1e30f;
#pragma unroll
            for (int oo = 0; oo < 16; ++oo) { l[oo] = sRaT[oo][t]; mx = fmaxf(mx, l[oo]); }
            float s = 0.f;
#pragma unroll
            for (int oo = 0; oo < 16; ++oo) { l[oo] = __expf(l[oo] - mx); s += l[oo]; }
            const float sc = sAct[t] / s;
#pragma unroll
            for (int oo = 0; oo < 16; ++oo) sRaT[oo][t] = sc * l[oo];
        }
        __syncthreads();   // B4: Ra ready
    }
}

extern "C" void kernel_launch(void* const* d_in, const int* in_sizes, int n_in,
                              void* d_out, int out_size, void* d_ws, size_t ws_size,
                              hipStream_t stream) {
    const float* pose = (const float*)d_in[0];
    const float* actv = (const float*)d_in[1];
    const float* W    = (const float*)d_in[2];
    const float* bv   = (const float*)d_in[3];
    const float* ba   = (const float*)d_in[4];
    float* out = (float*)d_out;
    caps_em_kernel<<<dim3(1000), dim3(512), 0, stream>>>(pose, actv, W, bv, ba, out);
}

// Round 15
// 154.365 us; speedup vs baseline: 1.1542x; 1.1542x over previous
//
#include <hip/hip_runtime.h>
#include <hip/hip_fp16.h>

#define NITER 3
#define LAMBDA 0.01f
#define EPS 1e-9f
#define LOG2PI 1.8378770664093453f

#define DIN 12
#define CIN 8
#define NI 216      // 27 * 8 input capsule-taps
#define NO 16       // output capsules
#define PPAD 20     // sPT row stride (floats)
#define RSTR 216    // sRaT row stride (floats)

// 1024 threads = 16 o-waves x 64 j. Thread (o,j) owns taps i = j+64k (k=0..3,
// padded to 256). fp16 votes vop[4][8] = 32 regs; half-sweep m-step (m1/m2[8]);
// peak live demand ~75-92 regs << 128 budget that a 1024-thr block mandates
// (16 waves = 4/SIMD) -> 50% occupancy, no AGPR split, no scratch (R9's bug
// was fp32 votes: 64+32+misc > 128 -> spill). sPT/sRaT aliased: LDS 20.5 KB.
__global__ __launch_bounds__(1024)
void caps_em_kernel(const float* __restrict__ pose,
                    const float* __restrict__ act,
                    const float* __restrict__ W,
                    const float* __restrict__ beta_v,
                    const float* __restrict__ beta_a,
                    float* __restrict__ out)
{
    // union region: max(sPT 216*20*4 = 17280 B, sRaT 16*216*4 = 13824 B)
    __shared__ __align__(16) char uBuf[17280];
    float (*sPT)[PPAD]  = (float (*)[PPAD])uBuf;   // valid until last prologue read
    float (*sRaT)[RSTR] = (float (*)[RSTR])uBuf;   // valid from e-step (it=0) on
    __shared__ float sAct[NI];
    __shared__ __align__(16) float sPoseM[NO][16];   // row-major [o][r*4+c]
    __shared__ __align__(16) float sIvM[NO][16];
    __shared__ float sCo[NO];

    const int t = threadIdx.x;
    const int b = blockIdx.x;            // 0..999 -> (od,oh,ow)
    const int od = b / 100;
    const int rem = b - od * 100;
    const int oh = rem / 10;
    const int ow = rem - oh * 10;

    const int o = t >> 6;                // output capsule == wave id (0..15)
    const int j = t & 63;                // i-lane 0..63

    // ---------- stage P (transposed) + act ----------
    if (t < NI * 4) {
        int i = t >> 2, q = t & 3;       // q = source row of the 4x4
        int ci = i & 7, n = i >> 3;
        int kw = n % 3, n2 = n / 3;
        int kh = n2 % 3, kd = n2 / 3;
        const float4 v = *(const float4*)&pose[((((od + kd) * DIN + (oh + kh)) * DIN + (ow + kw)) * CIN + ci) * 16 + q * 4];
        sPT[i][0 + q]  = v.x;
        sPT[i][4 + q]  = v.y;
        sPT[i][8 + q]  = v.z;
        sPT[i][12 + q] = v.w;
    }
    if (t < NI) {
        int i = t;
        int ci = i & 7, n = i >> 3;
        int kw = n % 3, n2 = n / 3;
        int kh = n2 % 3, kd = n2 / 3;
        sAct[i] = act[(((od + kd) * DIN + (oh + kh)) * DIN + (ow + kw)) * CIN + ci] + EPS;
    }
    const float bv_o = beta_v[o];
    const float ba_o = beta_a[o];
    __syncthreads();

    // ---------- votes ONCE, per-k interleaved load+compute ----------
    const float4* W4 = (const float4*)W;        // idx = (i*16 + o)*4 + r
    __half2 vop[4][8];                          // vop[k][p] = elements (2p, 2p+1)
#pragma unroll
    for (int k = 0; k < 4; ++k) {
        const int ip = min(j + 64 * k, NI - 1);
        const float4* Wp = W4 + (ip * 16 + o) * 4;
        const float4 w0 = Wp[0], w1 = Wp[1], w2 = Wp[2], w3 = Wp[3];
        float v16[16];
#pragma unroll
        for (int cc = 0; cc < 4; ++cc) {
            const float4 pt = *(const float4*)&sPT[ip][cc * 4];   // P[0..3][cc]
            v16[0 * 4 + cc]  = fmaf(w0.w, pt.w, fmaf(w0.z, pt.z, fmaf(w0.y, pt.y, w0.x * pt.x)));
            v16[1 * 4 + cc]  = fmaf(w1.w, pt.w, fmaf(w1.z, pt.z, fmaf(w1.y, pt.y, w1.x * pt.x)));
            v16[2 * 4 + cc]  = fmaf(w2.w, pt.w, fmaf(w2.z, pt.z, fmaf(w2.y, pt.y, w2.x * pt.x)));
            v16[3 * 4 + cc]  = fmaf(w3.w, pt.w, fmaf(w3.z, pt.z, fmaf(w3.y, pt.y, w3.x * pt.x)));
        }
#pragma unroll
        for (int p = 0; p < 8; ++p) {
            vop[k][p] = __floats2half2_rn(v16[2 * p], v16[2 * p + 1]);
        }
    }
    // All sPT reads complete before B2 (it=0); first sRaT write is after B2.

    const int b5 = (j >> 5) & 1, b4 = (j >> 4) & 1, b3 = (j >> 3) & 1;
    const bool lastPartial = (j >= 24);  // k=3 tap i=192+j valid only for j<24
    const int eL = (j >> 3) & 7;         // this lane's element within each half

    for (int it = 0; it < NITER; ++it) {
        // ---------- ra for own taps ----------
        float rak[4];
#pragma unroll
        for (int k = 0; k < 4; ++k) {
            const int ip = min(j + 64 * k, NI - 1);
            float ra = (it == 0) ? sAct[ip] * 0.0625f : sRaT[o][ip];
            if (k == 3 && lastPartial) ra = 0.f;
            rak[k] = ra;
        }
        float rs = rak[0] + rak[1] + rak[2] + rak[3];
        rs += __shfl_xor(rs, 32);
        rs += __shfl_xor(rs, 16);
        rs += __shfl_xor(rs, 8);
        rs += __shfl_xor(rs, 4);
        rs += __shfl_xor(rs, 2);
        rs += __shfl_xor(rs, 1);
        const float inv_rs = 1.0f / rs;

        float peA, ivA, lvA, peB, ivB, lvB;
        // ======== half sweeps: h=0 -> elements 0..7, h=1 -> 8..15 ========
#pragma unroll
        for (int h = 0; h < 2; ++h) {
            float m1[8], m2[8];
#pragma unroll
            for (int q = 0; q < 8; ++q) { m1[q] = 0.f; m2[q] = 0.f; }
#pragma unroll
            for (int k = 0; k < 4; ++k) {
                const float ra = rak[k];
#pragma unroll
                for (int p = 0; p < 4; ++p) {
                    const float2 f = __half22float2(vop[k][h * 4 + p]);
                    const float rv0 = ra * f.x;
                    const float rv1 = ra * f.y;
                    m1[2 * p]     += rv0;
                    m1[2 * p + 1] += rv1;
                    m2[2 * p]     = fmaf(rv0, f.x, m2[2 * p]);
                    m2[2 * p + 1] = fmaf(rv1, f.y, m2[2 * p + 1]);
                }
            }
            // 3-halving tree over 64 lanes: e_local = b5*4 + b4*2 + b3 = (j>>3)&7
#pragma unroll
            for (int q = 0; q < 4; ++q) {
                float s1 = b5 ? m1[q] : m1[q + 4];
                float s2 = b5 ? m2[q] : m2[q + 4];
                m1[q] = (b5 ? m1[q + 4] : m1[q]) + __shfl_xor(s1, 32);
                m2[q] = (b5 ? m2[q + 4] : m2[q]) + __shfl_xor(s2, 32);
            }
#pragma unroll
            for (int q = 0; q < 2; ++q) {
                float s1 = b4 ? m1[q] : m1[q + 2];
                float s2 = b4 ? m2[q] : m2[q + 2];
                m1[q] = (b4 ? m1[q + 2] : m1[q]) + __shfl_xor(s1, 16);
                m2[q] = (b4 ? m2[q + 2] : m2[q]) + __shfl_xor(s2, 16);
            }
            {
                float s1 = b3 ? m1[0] : m1[1];
                float s2 = b3 ? m2[0] : m2[1];
                m1[0] = (b3 ? m1[1] : m1[0]) + __shfl_xor(s1, 8);
                m2[0] = (b3 ? m2[1] : m2[0]) + __shfl_xor(s2, 8);
            }
            m1[0] += __shfl_xor(m1[0], 4);
            m2[0] += __shfl_xor(m2[0], 4);
            m1[0] += __shfl_xor(m1[0], 2);
            m2[0] += __shfl_xor(m2[0], 2);
            m1[0] += __shfl_xor(m1[0], 1);
            m2[0] += __shfl_xor(m2[0], 1);

            const float pe = m1[0] * inv_rs;
            const float ve = fmaxf(m2[0] * inv_rs - pe * pe, 0.0f) + EPS;
            if (h == 0) { peA = pe; ivA = 1.0f / ve; lvA = __logf(ve); }
            else        { peB = pe; ivB = 1.0f / ve; lvB = __logf(ve); }
        }

        // SL: lane holds lv for 2 of 16 elements, 8-fold duplicated across lanes
        float SL = lvA + lvB;
        SL += __shfl_xor(SL, 1);
        SL += __shfl_xor(SL, 2);
        SL += __shfl_xor(SL, 4);
        SL += __shfl_xor(SL, 8);
        SL += __shfl_xor(SL, 16);
        SL += __shfl_xor(SL, 32);
        SL *= 0.125f;

        const float cost  = rs * (16.0f * bv_o + 0.5f * SL);
        const float logit = LAMBDA * (ba_o - cost);

        if (it == NITER - 1) {
            if ((j & 7) == 0) {
                out[(b * NO + o) * 16 + eL]     = peA;
                out[(b * NO + o) * 16 + 8 + eL] = peB;
            }
            if (j == 0) out[256000 + b * NO + o] = 1.0f / (1.0f + __expf(-logit));
            return;
        }

        const float log_a = (logit >= 0.0f) ? -log1pf(__expf(-logit))
                                            : logit - log1pf(__expf(logit));
        if ((j & 7) == 0) {
            sPoseM[o][eL]     = peA;
            sPoseM[o][8 + eL] = peB;
            sIvM[o][eL]       = ivA;
            sIvM[o][8 + eL]   = ivB;
        }
        if (j == 0) sCo[o] = log_a - 0.5f * SL - 8.0f * LOG2PI;
        __syncthreads();   // B2: pose/iv/Co ready (also fences last sPT reads, it=0)

        // ---------- e-step: q-form from stored votes, two halves, qacc[4] ----------
        float qacc[4];
#pragma unroll
        for (int k = 0; k < 4; ++k) qacc[k] = 0.f;
#pragma unroll
        for (int h = 0; h < 2; ++h) {
            float pv[8], iv8[8];
            *(float4*)&pv[0]  = *(const float4*)&sPoseM[o][h * 8];
            *(float4*)&pv[4]  = *(const float4*)&sPoseM[o][h * 8 + 4];
            *(float4*)&iv8[0] = *(const float4*)&sIvM[o][h * 8];
            *(float4*)&iv8[4] = *(const float4*)&sIvM[o][h * 8 + 4];
#pragma unroll
            for (int k = 0; k < 4; ++k) {
                float q = qacc[k];
#pragma unroll
                for (int p = 0; p < 4; ++p) {
                    const float2 f = __half22float2(vop[k][h * 4 + p]);
                    const float d0 = f.x - pv[2 * p];
                    const float d1 = f.y - pv[2 * p + 1];
                    q = fmaf(d0 * d0, iv8[2 * p], q);
                    q = fmaf(d1 * d1, iv8[2 * p + 1], q);
                }
                qacc[k] = q;
            }
        }
        {
            const float Co = sCo[o];
#pragma unroll
            for (int k = 0; k < 4; ++k) {
                if (!(k == 3 && lastPartial)) {
                    sRaT[o][j + 64 * k] = Co - 0.5f * qacc[k];   // pre-norm logit
                }
            }
        }
        __syncthreads();   // B3: logits ready

        // ---------- R update: softmax over o, times act (4 threads per i) ----------
        if (t < NI * 4) {
            const int i = t >> 2, p = t & 3;     // lanes 4i..4i+3 share i
            float l[4];
            float mx = -1e30f;
#pragma unroll
            for (int q = 0; q < 4; ++q) { l[q] = sRaT[p * 4 + q][i]; mx = fmaxf(mx, l[q]); }
            mx = fmaxf(mx, __shfl_xor(mx, 1));
            mx = fmaxf(mx, __shfl_xor(mx, 2));
            float s = 0.f;
#pragma unroll
            for (int q = 0; q < 4; ++q) { l[q] = __expf(l[q] - mx); s += l[q]; }
            s += __shfl_xor(s, 1);
            s += __shfl_xor(s, 2);
            const float sc = sAct[i] / s;
#pragma unroll
            for (int q = 0; q < 4; ++q) sRaT[p * 4 + q][i] = sc * l[q];
        }
        __syncthreads();   // B4: Ra ready
    }
}

extern "C" void kernel_launch(void* const* d_in, const int* in_sizes, int n_in,
                              void* d_out, int out_size, void* d_ws, size_t ws_size,
                              hipStream_t stream) {
    const float* pose = (const float*)d_in[0];
    const float* actv = (const float*)d_in[1];
    const float* W    = (const float*)d_in[2];
    const float* bv   = (const float*)d_in[3];
    const float* ba   = (const float*)d_in[4];
    float* out = (float*)d_out;
    caps_em_kernel<<<dim3(1000), dim3(1024), 0, stream>>>(pose, actv, W, bv, ba, out);
}

// Round 16
// 147.207 us; speedup vs baseline: 1.2103x; 1.0486x over previous
//
#include <hip/hip_runtime.h>
#include <hip/hip_fp16.h>

#define NITER 3
#define LAMBDA 0.01f
#define EPS 1e-9f
#define LOG2PI 1.8378770664093453f

#define DIN 12
#define CIN 8
#define NI 216      // 27 * 8 input capsule-taps
#define NO 16       // output capsules
#define NK 14       // taps per thread (16 j-lanes: 14*16 = 224 >= 216)
#define PPAD 20     // sPT row stride (floats)
#define RSTR 216    // sRaT row stride (floats)

// 256 threads = 16 o x 16 j. Thread (o,j) owns taps i = j+16k (k=0..13, padded).
// Same math as R13 (fp16 votes, half-sweep moments, aliased sPT/sRaT LDS).
// WHY 256: blocks contribute 1 wave/SIMD each -> at ~160-reg demand, 3 blocks
// co-reside (3x160=480 <= 512-reg unified file) vs 512-thr's hard 1-block cap
// (2 waves/SIMD x 156 x 2 blocks > 512). No launch-bound forcing -> no spill
// (R4/R9/R14/R15 lesson: forcing a budget makes the RA spill to scratch).
// ALL shuffles use distance <= 8: a wave spans 4 o-groups of 16 lanes.
__global__ __launch_bounds__(256)
void caps_em_kernel(const float* __restrict__ pose,
                    const float* __restrict__ act,
                    const float* __restrict__ W,
                    const float* __restrict__ beta_v,
                    const float* __restrict__ beta_a,
                    float* __restrict__ out)
{
    // union region: max(sPT 216*20*4 = 17280 B, sRaT 16*216*4 = 13824 B)
    __shared__ __align__(16) char uBuf[17280];
    float (*sPT)[PPAD]  = (float (*)[PPAD])uBuf;   // valid until last prologue read
    float (*sRaT)[RSTR] = (float (*)[RSTR])uBuf;   // valid from e-step (it=0) on
    __shared__ float sAct[NI];
    __shared__ __align__(16) float sPoseM[NO][16];   // row-major [o][r*4+c]
    __shared__ __align__(16) float sIvM[NO][16];
    __shared__ float sCo[NO];

    const int t = threadIdx.x;
    const int b = blockIdx.x;            // 0..999 -> (od,oh,ow)
    const int od = b / 100;
    const int rem = b - od * 100;
    const int oh = rem / 10;
    const int ow = rem - oh * 10;

    const int o = t >> 4;                // output capsule 0..15
    const int j = t & 15;                // i-lane 0..15

    // ---------- stage P (transposed) + act ----------
    for (int u = t; u < NI * 4; u += 256) {
        int i = u >> 2, q = u & 3;       // q = source row of the 4x4
        int ci = i & 7, n = i >> 3;
        int kw = n % 3, n2 = n / 3;
        int kh = n2 % 3, kd = n2 / 3;
        const float4 v = *(const float4*)&pose[((((od + kd) * DIN + (oh + kh)) * DIN + (ow + kw)) * CIN + ci) * 16 + q * 4];
        sPT[i][0 + q]  = v.x;
        sPT[i][4 + q]  = v.y;
        sPT[i][8 + q]  = v.z;
        sPT[i][12 + q] = v.w;
    }
    if (t < NI) {
        int i = t;
        int ci = i & 7, n = i >> 3;
        int kw = n % 3, n2 = n / 3;
        int kh = n2 % 3, kd = n2 / 3;
        sAct[i] = act[(((od + kd) * DIN + (oh + kh)) * DIN + (ow + kw)) * CIN + ci] + EPS;
    }
    const float bv_o = beta_v[o];
    const float ba_o = beta_a[o];
    __syncthreads();

    // ---------- votes ONCE, per-k interleaved load+compute ----------
    const float4* W4 = (const float4*)W;        // idx = (i*16 + o)*4 + r
    __half2 vop[NK][8];                         // vop[k][p] = elements (2p, 2p+1)
#pragma unroll
    for (int k = 0; k < NK; ++k) {
        const int ip = min(j + 16 * k, NI - 1);
        const float4* Wp = W4 + (ip * 16 + o) * 4;
        const float4 w0 = Wp[0], w1 = Wp[1], w2 = Wp[2], w3 = Wp[3];
        float v16[16];
#pragma unroll
        for (int cc = 0; cc < 4; ++cc) {
            const float4 pt = *(const float4*)&sPT[ip][cc * 4];   // P[0..3][cc]
            v16[0 * 4 + cc]  = fmaf(w0.w, pt.w, fmaf(w0.z, pt.z, fmaf(w0.y, pt.y, w0.x * pt.x)));
            v16[1 * 4 + cc]  = fmaf(w1.w, pt.w, fmaf(w1.z, pt.z, fmaf(w1.y, pt.y, w1.x * pt.x)));
            v16[2 * 4 + cc]  = fmaf(w2.w, pt.w, fmaf(w2.z, pt.z, fmaf(w2.y, pt.y, w2.x * pt.x)));
            v16[3 * 4 + cc]  = fmaf(w3.w, pt.w, fmaf(w3.z, pt.z, fmaf(w3.y, pt.y, w3.x * pt.x)));
        }
#pragma unroll
        for (int p = 0; p < 8; ++p) {
            vop[k][p] = __floats2half2_rn(v16[2 * p], v16[2 * p + 1]);
        }
    }
    // All sPT reads complete before B2 (it=0); first sRaT write is after B2.

    const int b3 = (j >> 3) & 1, b2 = (j >> 2) & 1, b1 = (j >> 1) & 1;
    const bool lastPartial = (j >= 8);   // k=13 tap i=208+j valid only for j<8
    const int eL = (j >> 1) & 7;         // this lane's element within each half

    for (int it = 0; it < NITER; ++it) {
        // ---------- ra for own taps ----------
        float rak[NK];
        float rs = 0.f;
#pragma unroll
        for (int k = 0; k < NK; ++k) {
            const int ip = min(j + 16 * k, NI - 1);
            float ra = (it == 0) ? sAct[ip] * 0.0625f : sRaT[o][ip];
            if (k == NK - 1 && lastPartial) ra = 0.f;
            rak[k] = ra;
            rs += ra;
        }
        rs += __shfl_xor(rs, 8);
        rs += __shfl_xor(rs, 4);
        rs += __shfl_xor(rs, 2);
        rs += __shfl_xor(rs, 1);
        const float inv_rs = 1.0f / rs;

        float peA, ivA, lvA, peB, ivB, lvB;
        // ======== half sweeps: h=0 -> elements 0..7, h=1 -> 8..15 ========
#pragma unroll
        for (int h = 0; h < 2; ++h) {
            float m1[8], m2[8];
#pragma unroll
            for (int q = 0; q < 8; ++q) { m1[q] = 0.f; m2[q] = 0.f; }
#pragma unroll
            for (int k = 0; k < NK; ++k) {
                const float ra = rak[k];
#pragma unroll
                for (int p = 0; p < 4; ++p) {
                    const float2 f = __half22float2(vop[k][h * 4 + p]);
                    const float rv0 = ra * f.x;
                    const float rv1 = ra * f.y;
                    m1[2 * p]     += rv0;
                    m1[2 * p + 1] += rv1;
                    m2[2 * p]     = fmaf(rv0, f.x, m2[2 * p]);
                    m2[2 * p + 1] = fmaf(rv1, f.y, m2[2 * p + 1]);
                }
            }
            // 3-halving tree over the 16 j-lanes (distances 8/4/2, intra-o),
            // then xor1 dup-add. Lane ends with element h*8 + (b3*4+b2*2+b1).
#pragma unroll
            for (int q = 0; q < 4; ++q) {
                float s1 = b3 ? m1[q] : m1[q + 4];
                float s2 = b3 ? m2[q] : m2[q + 4];
                m1[q] = (b3 ? m1[q + 4] : m1[q]) + __shfl_xor(s1, 8);
                m2[q] = (b3 ? m2[q + 4] : m2[q]) + __shfl_xor(s2, 8);
            }
#pragma unroll
            for (int q = 0; q < 2; ++q) {
                float s1 = b2 ? m1[q] : m1[q + 2];
                float s2 = b2 ? m2[q] : m2[q + 2];
                m1[q] = (b2 ? m1[q + 2] : m1[q]) + __shfl_xor(s1, 4);
                m2[q] = (b2 ? m2[q + 2] : m2[q]) + __shfl_xor(s2, 4);
            }
            {
                float s1 = b1 ? m1[0] : m1[1];
                float s2 = b1 ? m2[0] : m2[1];
                m1[0] = (b1 ? m1[1] : m1[0]) + __shfl_xor(s1, 2);
                m2[0] = (b1 ? m2[1] : m2[0]) + __shfl_xor(s2, 2);
            }
            m1[0] += __shfl_xor(m1[0], 1);
            m2[0] += __shfl_xor(m2[0], 1);

            const float pe = m1[0] * inv_rs;
            const float ve = fmaxf(m2[0] * inv_rs - pe * pe, 0.0f) + EPS;
            if (h == 0) { peA = pe; ivA = 1.0f / ve; lvA = __logf(ve); }
            else        { peB = pe; ivB = 1.0f / ve; lvB = __logf(ve); }
        }

        // SL: lane holds lv for 2 of 16 elements, 2-fold duplicated across lanes
        float SL = lvA + lvB;
        SL += __shfl_xor(SL, 1);
        SL += __shfl_xor(SL, 2);
        SL += __shfl_xor(SL, 4);
        SL += __shfl_xor(SL, 8);
        SL *= 0.5f;

        const float cost  = rs * (16.0f * bv_o + 0.5f * SL);
        const float logit = LAMBDA * (ba_o - cost);

        if (it == NITER - 1) {
            if ((j & 1) == 0) {
                out[(b * NO + o) * 16 + eL]     = peA;
                out[(b * NO + o) * 16 + 8 + eL] = peB;
            }
            if (j == 0) out[256000 + b * NO + o] = 1.0f / (1.0f + __expf(-logit));
            return;
        }

        const float log_a = (logit >= 0.0f) ? -log1pf(__expf(-logit))
                                            : logit - log1pf(__expf(logit));
        if ((j & 1) == 0) {
            sPoseM[o][eL]     = peA;
            sPoseM[o][8 + eL] = peB;
            sIvM[o][eL]       = ivA;
            sIvM[o][8 + eL]   = ivB;
        }
        if (j == 0) sCo[o] = log_a - 0.5f * SL - 8.0f * LOG2PI;
        __syncthreads();   // B2: pose/iv/Co ready (also fences last sPT reads, it=0)

        // ---------- e-step: q-form from stored votes, two halves, qacc[NK] ----------
        float qacc[NK];
#pragma unroll
        for (int k = 0; k < NK; ++k) qacc[k] = 0.f;
#pragma unroll
        for (int h = 0; h < 2; ++h) {
            float pv[8], iv8[8];
            *(float4*)&pv[0]  = *(const float4*)&sPoseM[o][h * 8];
            *(float4*)&pv[4]  = *(const float4*)&sPoseM[o][h * 8 + 4];
            *(float4*)&iv8[0] = *(const float4*)&sIvM[o][h * 8];
            *(float4*)&iv8[4] = *(const float4*)&sIvM[o][h * 8 + 4];
#pragma unroll
            for (int k = 0; k < NK; ++k) {
                float q = qacc[k];
#pragma unroll
                for (int p = 0; p < 4; ++p) {
                    const float2 f = __half22float2(vop[k][h * 4 + p]);
                    const float d0 = f.x - pv[2 * p];
                    const float d1 = f.y - pv[2 * p + 1];
                    q = fmaf(d0 * d0, iv8[2 * p], q);
                    q = fmaf(d1 * d1, iv8[2 * p + 1], q);
                }
                qacc[k] = q;
            }
        }
        {
            const float Co = sCo[o];
#pragma unroll
            for (int k = 0; k < NK; ++k) {
                if (!(k == NK - 1 && lastPartial)) {
                    sRaT[o][j + 16 * k] = Co - 0.5f * qacc[k];   // pre-norm logit
                }
            }
        }
        __syncthreads();   // B3: logits ready

        // ---------- R update: softmax over o, times act ----------
        if (t < NI) {
            float l[16];
            float mx = -1e30f;
#pragma unroll
            for (int oo = 0; oo < 16; ++oo) { l[oo] = sRaT[oo][t]; mx = fmaxf(mx, l[oo]); }
            float s = 0.f;
#pragma unroll
            for (int oo = 0; oo < 16; ++oo) { l[oo] = __expf(l[oo] - mx); s += l[oo]; }
            const float sc = sAct[t] / s;
#pragma unroll
            for (int oo = 0; oo < 16; ++oo) sRaT[oo][t] = sc * l[oo];
        }
        __syncthreads();   // B4: Ra ready
    }
}

extern "C" void kernel_launch(void* const* d_in, const int* in_sizes, int n_in,
                              void* d_out, int out_size, void* d_ws, size_t ws_size,
                              hipStream_t stream) {
    const float* pose = (const float*)d_in[0];
    const float* actv = (const float*)d_in[1];
    const float* W    = (const float*)d_in[2];
    const float* bv   = (const float*)d_in[3];
    const float* ba   = (const float*)d_in[4];
    float* out = (float*)d_out;
    caps_em_kernel<<<dim3(1000), dim3(256), 0, stream>>>(pose, actv, W, bv, ba, out);
}

// Round 17
// 132.121 us; speedup vs baseline: 1.3485x; 1.1142x over previous
//
#include <hip/hip_runtime.h>
#include <hip/hip_fp16.h>

#define NITER 3
#define LAMBDA 0.01f
#define EPS 1e-9f
#define LOG2PI 1.8378770664093453f

#define DIN 12
#define CIN 8
#define NI 216      // 27 * 8 input capsule-taps
#define NO 16       // output capsules
#define NK 7        // taps per thread (32 j-lanes x 7 = 224 >= 216)
#define PPAD 20     // sPT row stride (floats)

// 512 threads, TRANSPOSED map: o = t&15 (16 contiguous lanes per tap-group),
// j = t>>4 (0..31). Taps i = j+32k. fp16 votes vop[7][8] = 56 regs.
// KEY: softmax over o is now 8 intra-wave shuffles per tap, fused into the
// e-step; Ra lives in registers (rak[7]) across iterations -> no sRaT LDS, no
// serial softmax phase, 2 barriers/iter instead of 3. Moment reduction:
// 2 intra-wave halvings (xor16/32) + one LDS scatter + 256-thread stats phase.
__global__ __launch_bounds__(512)
void caps_em_kernel(const float* __restrict__ pose,
                    const float* __restrict__ act,
                    const float* __restrict__ W,
                    const float* __restrict__ beta_v,
                    const float* __restrict__ beta_a,
                    float* __restrict__ out)
{
    __shared__ __align__(16) float sPT[NI][PPAD];    // pose cols: sPT[i][c*4+k]
    __shared__ __align__(16) float sM1[16][17][8];   // [e][o pad17][wave]
    __shared__ __align__(16) float sM2[16][17][8];
    __shared__ float sRs[16][8];                     // [o][wave]
    __shared__ float sAct[NI];
    __shared__ __align__(16) float sPoseM[NO][16];   // row-major [o][r*4+c]
    __shared__ __align__(16) float sIvM[NO][16];
    __shared__ float sCo[NO];
    __shared__ float sBv[NO];
    __shared__ float sBa[NO];

    const int t = threadIdx.x;
    const int b = blockIdx.x;            // 0..999 -> (od,oh,ow)
    const int od = b / 100;
    const int rem = b - od * 100;
    const int oh = rem / 10;
    const int ow = rem - oh * 10;

    const int o = t & 15;                // output capsule (contiguous lanes!)
    const int j = t >> 4;                // i-lane 0..31

    // ---------- stage P (transposed) + act + betas ----------
    for (int u = t; u < NI * 4; u += 512) {
        int i = u >> 2, q = u & 3;       // q = source row of the 4x4
        int ci = i & 7, n = i >> 3;
        int kw = n % 3, n2 = n / 3;
        int kh = n2 % 3, kd = n2 / 3;
        const float4 v = *(const float4*)&pose[((((od + kd) * DIN + (oh + kh)) * DIN + (ow + kw)) * CIN + ci) * 16 + q * 4];
        sPT[i][0 + q]  = v.x;
        sPT[i][4 + q]  = v.y;
        sPT[i][8 + q]  = v.z;
        sPT[i][12 + q] = v.w;
    }
    if (t < NI) {
        int i = t;
        int ci = i & 7, n = i >> 3;
        int kw = n % 3, n2 = n / 3;
        int kh = n2 % 3, kd = n2 / 3;
        sAct[i] = act[(((od + kd) * DIN + (oh + kh)) * DIN + (ow + kw)) * CIN + ci] + EPS;
    }
    if (t < NO) { sBv[t] = beta_v[t]; sBa[t] = beta_a[t]; }
    __syncthreads();

    // ---------- votes ONCE, per-k interleaved load+compute ----------
    const float4* W4 = (const float4*)W;        // idx = (i*16 + o)*4 + r
    __half2 vop[NK][8];                         // vop[k][p] = elements (2p, 2p+1)
#pragma unroll
    for (int k = 0; k < NK; ++k) {
        const int ip = min(j + 32 * k, NI - 1);
        const float4* Wp = W4 + (ip * 16 + o) * 4;
        const float4 w0 = Wp[0], w1 = Wp[1], w2 = Wp[2], w3 = Wp[3];
        float v16[16];
#pragma unroll
        for (int cc = 0; cc < 4; ++cc) {
            const float4 pt = *(const float4*)&sPT[ip][cc * 4];   // broadcast (o-lanes share ip)
            v16[0 * 4 + cc]  = fmaf(w0.w, pt.w, fmaf(w0.z, pt.z, fmaf(w0.y, pt.y, w0.x * pt.x)));
            v16[1 * 4 + cc]  = fmaf(w1.w, pt.w, fmaf(w1.z, pt.z, fmaf(w1.y, pt.y, w1.x * pt.x)));
            v16[2 * 4 + cc]  = fmaf(w2.w, pt.w, fmaf(w2.z, pt.z, fmaf(w2.y, pt.y, w2.x * pt.x)));
            v16[3 * 4 + cc]  = fmaf(w3.w, pt.w, fmaf(w3.z, pt.z, fmaf(w3.y, pt.y, w3.x * pt.x)));
        }
#pragma unroll
        for (int p = 0; p < 8; ++p) {
            vop[k][p] = __floats2half2_rn(v16[2 * p], v16[2 * p + 1]);
        }
    }

    // lane-geometry constants: within a wave, lane bits 4..5 = j&3
    const int b0 = j & 1;                // lane bit4 -> shuffle dist 16
    const int b1v = (j >> 1) & 1;        // lane bit5 -> shuffle dist 32
    const int w = j >> 2;                // wave id 0..7
    const int eb = b0 * 4 + b1v * 2;     // element base within half
    const bool lastPartial = (j >= 24);  // k=6 tap i=192+j valid only for j<24

    // Ra for it=0: uniform act/16, kept in registers across iterations
    float rak[NK];
#pragma unroll
    for (int k = 0; k < NK; ++k) {
        const int ip = min(j + 32 * k, NI - 1);
        rak[k] = sAct[ip] * 0.0625f;
        if (k == NK - 1 && lastPartial) rak[k] = 0.f;
    }

    for (int it = 0; it < NITER; ++it) {
        // ---------- m-pass: moments from stored votes, Ra from registers ----------
        float rsp = ((rak[0] + rak[1]) + (rak[2] + rak[3])) + ((rak[4] + rak[5]) + rak[6]);
        rsp += __shfl_xor(rsp, 16);
        rsp += __shfl_xor(rsp, 32);          // per-wave, per-o partial of rs

        float p1[2][2], p2[2][2];
#pragma unroll
        for (int h = 0; h < 2; ++h) {
            float m1[8], m2[8];
#pragma unroll
            for (int q = 0; q < 8; ++q) { m1[q] = 0.f; m2[q] = 0.f; }
#pragma unroll
            for (int k = 0; k < NK; ++k) {
                const float ra = rak[k];
#pragma unroll
                for (int p = 0; p < 4; ++p) {
                    const float2 f = __half22float2(vop[k][h * 4 + p]);
                    const float rv0 = ra * f.x;
                    const float rv1 = ra * f.y;
                    m1[2 * p]     += rv0;
                    m1[2 * p + 1] += rv1;
                    m2[2 * p]     = fmaf(rv0, f.x, m2[2 * p]);
                    m2[2 * p + 1] = fmaf(rv1, f.y, m2[2 * p + 1]);
                }
            }
            // intra-wave halvings over j&3: xor16 (b0), xor32 (b1v)
#pragma unroll
            for (int q = 0; q < 4; ++q) {
                float s1 = b0 ? m1[q] : m1[q + 4];
                float s2 = b0 ? m2[q] : m2[q + 4];
                m1[q] = (b0 ? m1[q + 4] : m1[q]) + __shfl_xor(s1, 16);
                m2[q] = (b0 ? m2[q + 4] : m2[q]) + __shfl_xor(s2, 16);
            }
#pragma unroll
            for (int q = 0; q < 2; ++q) {
                float s1 = b1v ? m1[q] : m1[q + 2];
                float s2 = b1v ? m2[q] : m2[q + 2];
                m1[q] = (b1v ? m1[q + 2] : m1[q]) + __shfl_xor(s1, 32);
                m2[q] = (b1v ? m2[q + 2] : m2[q]) + __shfl_xor(s2, 32);
            }
            p1[h][0] = m1[0]; p1[h][1] = m1[1];
            p2[h][0] = m2[0]; p2[h][1] = m2[1];
        }
        // scatter wave partials: element e = h*8 + eb + q
#pragma unroll
        for (int h = 0; h < 2; ++h) {
#pragma unroll
            for (int q = 0; q < 2; ++q) {
                sM1[h * 8 + eb + q][o][w] = p1[h][q];
                sM2[h * 8 + eb + q][o][w] = p2[h][q];
            }
        }
        if ((j & 3) == 0) sRs[o][w] = rsp;
        __syncthreads();   // B1: wave partials ready

        // ---------- stats phase: 256 threads own the 256 (o,e) pairs ----------
        if (it == NITER - 1) {
            if (t < 256) {
                const int o2 = t >> 4, e2 = t & 15;
                const float4 a0 = *(const float4*)&sM1[e2][o2][0];
                const float4 a1 = *(const float4*)&sM1[e2][o2][4];
                const float4 c0 = *(const float4*)&sM2[e2][o2][0];
                const float4 c1 = *(const float4*)&sM2[e2][o2][4];
                const float m1s = ((a0.x + a0.y) + (a0.z + a0.w)) + ((a1.x + a1.y) + (a1.z + a1.w));
                const float m2s = ((c0.x + c0.y) + (c0.z + c0.w)) + ((c1.x + c1.y) + (c1.z + c1.w));
                float rs = 0.f;
#pragma unroll
                for (int ww = 0; ww < 8; ++ww) rs += sRs[o2][ww];
                const float inv_rs = 1.0f / rs;
                const float pe = m1s * inv_rs;
                const float ve = fmaxf(m2s * inv_rs - pe * pe, 0.0f) + EPS;
                float SL = __logf(ve);
                SL += __shfl_xor(SL, 1);
                SL += __shfl_xor(SL, 2);
                SL += __shfl_xor(SL, 4);
                SL += __shfl_xor(SL, 8);
                const float cost  = rs * (16.0f * sBv[o2] + 0.5f * SL);
                const float logit = LAMBDA * (sBa[o2] - cost);
                out[(b * NO + o2) * 16 + e2] = pe;
                if (e2 == 0) out[256000 + b * NO + o2] = 1.0f / (1.0f + __expf(-logit));
            }
            return;
        }
        if (t < 256) {
            const int o2 = t >> 4, e2 = t & 15;
            const float4 a0 = *(const float4*)&sM1[e2][o2][0];
            const float4 a1 = *(const float4*)&sM1[e2][o2][4];
            const float4 c0 = *(const float4*)&sM2[e2][o2][0];
            const float4 c1 = *(const float4*)&sM2[e2][o2][4];
            const float m1s = ((a0.x + a0.y) + (a0.z + a0.w)) + ((a1.x + a1.y) + (a1.z + a1.w));
            const float m2s = ((c0.x + c0.y) + (c0.z + c0.w)) + ((c1.x + c1.y) + (c1.z + c1.w));
            float rs = 0.f;
#pragma unroll
            for (int ww = 0; ww < 8; ++ww) rs += sRs[o2][ww];
            const float inv_rs = 1.0f / rs;
            const float pe = m1s * inv_rs;
            const float ve = fmaxf(m2s * inv_rs - pe * pe, 0.0f) + EPS;
            float SL = __logf(ve);
            SL += __shfl_xor(SL, 1);
            SL += __shfl_xor(SL, 2);
            SL += __shfl_xor(SL, 4);
            SL += __shfl_xor(SL, 8);
            const float cost  = rs * (16.0f * sBv[o2] + 0.5f * SL);
            const float logit = LAMBDA * (sBa[o2] - cost);
            const float log_a = (logit >= 0.0f) ? -log1pf(__expf(-logit))
                                                : logit - log1pf(__expf(logit));
            sPoseM[o2][e2] = pe;
            sIvM[o2][e2]   = 1.0f / ve;
            if (e2 == 0) sCo[o2] = log_a - 0.5f * SL - 8.0f * LOG2PI;
        }
        __syncthreads();   // B2: pose/iv/Co ready

        // ---------- e-step + FUSED softmax (Ra stays in registers) ----------
        {
            float pv[16], iv16[16];
            *(float4*)&pv[0]    = *(const float4*)&sPoseM[o][0];
            *(float4*)&pv[4]    = *(const float4*)&sPoseM[o][4];
            *(float4*)&pv[8]    = *(const float4*)&sPoseM[o][8];
            *(float4*)&pv[12]   = *(const float4*)&sPoseM[o][12];
            *(float4*)&iv16[0]  = *(const float4*)&sIvM[o][0];
            *(float4*)&iv16[4]  = *(const float4*)&sIvM[o][4];
            *(float4*)&iv16[8]  = *(const float4*)&sIvM[o][8];
            *(float4*)&iv16[12] = *(const float4*)&sIvM[o][12];
            const float Co = sCo[o];
#pragma unroll
            for (int k = 0; k < NK; ++k) {
                float qf = 0.f;
#pragma unroll
                for (int p = 0; p < 8; ++p) {
                    const float2 f = __half22float2(vop[k][p]);
                    const float d0 = f.x - pv[2 * p];
                    const float d1 = f.y - pv[2 * p + 1];
                    qf = fmaf(d0 * d0, iv16[2 * p], qf);
                    qf = fmaf(d1 * d1, iv16[2 * p + 1], qf);
                }
                const float l = Co - 0.5f * qf;       // pre-norm logit for (i, o)
                // softmax over o: the 16 o-lanes of this tap are contiguous
                float mx = l;
                mx = fmaxf(mx, __shfl_xor(mx, 1));
                mx = fmaxf(mx, __shfl_xor(mx, 2));
                mx = fmaxf(mx, __shfl_xor(mx, 4));
                mx = fmaxf(mx, __shfl_xor(mx, 8));
                const float ex = __expf(l - mx);
                float s = ex;
                s += __shfl_xor(s, 1);
                s += __shfl_xor(s, 2);
                s += __shfl_xor(s, 4);
                s += __shfl_xor(s, 8);
                const int ip = min(j + 32 * k, NI - 1);
                rak[k] = sAct[ip] * ex / s;
                if (k == NK - 1 && lastPartial) rak[k] = 0.f;
            }
        }
    }
}

extern "C" void kernel_launch(void* const* d_in, const int* in_sizes, int n_in,
                              void* d_out, int out_size, void* d_ws, size_t ws_size,
                              hipStream_t stream) {
    const float* pose = (const float*)d_in[0];
    const float* actv = (const float*)d_in[1];
    const float* W    = (const float*)d_in[2];
    const float* bv   = (const float*)d_in[3];
    const float* ba   = (const float*)d_in[4];
    float* out = (float*)d_out;
    caps_em_kernel<<<dim3(1000), dim3(512), 0, stream>>>(pose, actv, W, bv, ba, out);
}